// Round 8
// baseline (394.162 us; speedup 1.0000x reference)
//
#include <hip/hip_runtime.h>
#include <hip/hip_bf16.h>

// ---------------------------------------------------------------------------
// GCNEncoder: 3x (GCNConv -> [BN -> LeakyReLU]), N=50000 nodes, E=800000 edges.
//   Layer1 aggregate-first:  out1 = (A_hat X) W1 + b1
//   Layers2/3 transform-first: hd = (act(prev) @ W) * dinv; out = gather + bias
// R8: plane-split gather. Gathered buffers (xs, hd2, hd3) stored as TWO
//     channel-planes of 3.2MB ([2][n][16] uint32). agg blocks pick plane by
//     blockIdx&1 -> with round-robin block->XCD dispatch each XCD's L2 (4MiB)
//     only sees ONE plane -> random gathers become L2 hits instead of L3
//     misses (R7 model: 6.4MB buffer > 4MiB L2 -> miss-concurrency bound,
//     ~45us/agg). Same gather instruction count (4 edges x 64B per instr).
// ---------------------------------------------------------------------------

#define LEAKY 0.01f
#define EPS_BN 1e-5f

typedef unsigned int uint32;

static __device__ __forceinline__ float bf_lo(uint32 u) { return __uint_as_float(u << 16); }
static __device__ __forceinline__ float bf_hi(uint32 u) { return __uint_as_float(u & 0xFFFF0000u); }

static __device__ __forceinline__ uint32 pack_bf(float x, float y) {
    __hip_bfloat16 bx = __float2bfloat16(x), by = __float2bfloat16(y);
    return (uint32)(*(unsigned short*)&bx) | ((uint32)(*(unsigned short*)&by) << 16);
}

// ---------------- setup: zero scratch + detect dtype + convert params -------
// blocks [0,83): detect flag (redundantly per block) + convert param slice
// blocks [83,..): zero cnt / cursor / stats1 / stats2
// param dst layout: W1@0(8192) b1@8192(128) g1@8320(128) be1@8448(128)
//   W2@8576(8192) b2@16768(64) g2@16832(64) be2@16896(64) W3@16960(4096) b3@21056(64)

__global__ void setup_k(const uint32* __restrict__ x, int* __restrict__ flag,
                        const void* p0, const void* p1, const void* p2,
                        const void* p3, const void* p4, const void* p5,
                        const void* p6, const void* p7, const void* p8,
                        const void* p9, float* __restrict__ dst,
                        int* __restrict__ cnt, int* __restrict__ cursor,
                        float* __restrict__ stats1, float* __restrict__ stats2,
                        int n) {
    const int b = blockIdx.x, t = threadIdx.x;
    if (b < 83) {
        __shared__ int sd[256];
        int c = 0;
        for (int j = 0; j < 16; ++j) {
            uint32 w = x[t * 16 + j];
            uint32 m = w & 0x7FFFu;
            uint32 e = (w >> 7) & 0xFFu;
            if (m == 0u || (e >= 100u && e <= 150u)) ++c;
        }
        sd[t] = c;
        __syncthreads();
        for (int off = 128; off > 0; off >>= 1) {
            if (t < off) sd[t] += sd[t + off];
            __syncthreads();
        }
        bool bf = (sd[0] >= 3072);
        if (b == 0 && t == 0) *flag = bf ? 1 : 0;
        int i = b * 256 + t;
        if (i < 21120) {
            const void* p;
            int j;
            if      (i <  8192) { p = p0; j = i;         }
            else if (i <  8320) { p = p1; j = i - 8192;  }
            else if (i <  8448) { p = p2; j = i - 8320;  }
            else if (i <  8576) { p = p3; j = i - 8448;  }
            else if (i < 16768) { p = p4; j = i - 8576;  }
            else if (i < 16832) { p = p5; j = i - 16768; }
            else if (i < 16896) { p = p6; j = i - 16832; }
            else if (i < 16960) { p = p7; j = i - 16896; }
            else if (i < 21056) { p = p8; j = i - 16960; }
            else                { p = p9; j = i - 21056; }
            dst[i] = bf ? __bfloat162float(((const __hip_bfloat16*)p)[j])
                        : ((const float*)p)[j];
        }
    } else {
        int idx = (b - 83) * 256 + t;
        if      (idx < n)           cnt[idx] = 0;
        else if (idx < 2 * n)       cursor[idx - n] = 0;
        else if (idx < 2 * n + 256) stats1[idx - 2 * n] = 0;
        else if (idx < 2 * n + 384) stats2[idx - 2 * n - 256] = 0;
    }
}

// ---------------- degree histogram, XCD-binned ----------------

__global__ __launch_bounds__(256) void hist_bin_k(const int* __restrict__ dst,
                                                  int* __restrict__ cnt,
                                                  int E, int n) {
    const int bin = blockIdx.x & 7;
    const int lo  = (bin * n) / 8;
    const int hi  = ((bin + 1) * n) / 8;
    const int stride = (gridDim.x >> 3) * 256;
    for (int i = (blockIdx.x >> 3) * 256 + threadIdx.x; i < E; i += stride) {
        int d = dst[i];
        if (d >= lo && d < hi) atomicAdd(&cnt[d], 1);
    }
}

__global__ void chunk_sum_k(const int* __restrict__ cnt, int* __restrict__ csum, int n) {
    __shared__ int sd[256];
    int i = blockIdx.x * 256 + threadIdx.x;
    sd[threadIdx.x] = (i < n) ? cnt[i] : 0;
    __syncthreads();
    for (int off = 128; off > 0; off >>= 1) {
        if (threadIdx.x < off) sd[threadIdx.x] += sd[threadIdx.x + off];
        __syncthreads();
    }
    if (threadIdx.x == 0) csum[blockIdx.x] = sd[0];
}

// single block, nchunk <= 256
__global__ void chunk_scan_k(const int* __restrict__ csum, int* __restrict__ coff,
                             int nchunk, int* __restrict__ row_end, int total) {
    __shared__ int sd[256];
    int t = threadIdx.x;
    int v = (t < nchunk) ? csum[t] : 0;
    sd[t] = v;
    __syncthreads();
    for (int off = 1; off < 256; off <<= 1) {
        int x = (t >= off) ? sd[t - off] : 0;
        __syncthreads();
        sd[t] += x;
        __syncthreads();
    }
    if (t < nchunk) coff[t] = sd[t] - v;   // exclusive
    if (t == 0) *row_end = total;          // row_start[n] = E
}

__global__ void local_scan_k(const int* __restrict__ cnt, const int* __restrict__ coff,
                             int* __restrict__ row_start, int n) {
    __shared__ int sd[256];
    int i = blockIdx.x * 256 + threadIdx.x;
    int v = (i < n) ? cnt[i] : 0;
    sd[threadIdx.x] = v;
    __syncthreads();
    for (int off = 1; off < 256; off <<= 1) {
        int x = (threadIdx.x >= off) ? sd[threadIdx.x - off] : 0;
        __syncthreads();
        sd[threadIdx.x] += x;
        __syncthreads();
    }
    if (i < n) row_start[i] = coff[blockIdx.x] + sd[threadIdx.x] - v;
}

// ---------------- build: binned CSR fill + dinv + xs = x*dinv (split) ------
// blocks [0,fb): binned elist scatter. blocks [fb,..): xs (plane-split) + dinv.
// xs layout: plane p in {0,1}: xs[p*n*16 + v*16 + c] = channels (p*32+2c, +1).

__global__ __launch_bounds__(256) void build_k(
    const int* __restrict__ src, const int* __restrict__ dst,
    const int* __restrict__ row_start, int* __restrict__ cursor,
    int* __restrict__ elist, const int* __restrict__ cnt,
    const void* __restrict__ xv, const int* __restrict__ flag,
    uint32* __restrict__ xs, float* __restrict__ dinv,
    int E, int n, int fb) {
    const int b = blockIdx.x;
    if (b < fb) {
        const int bin = b & 7;
        const int lo  = (bin * n) / 8;
        const int hi  = ((bin + 1) * n) / 8;
        const int stride = (fb >> 3) * 256;
        for (int i = (b >> 3) * 256 + threadIdx.x; i < E; i += stride) {
            int d = dst[i];
            if (d >= lo && d < hi) {
                int pos = atomicAdd(&cursor[d], 1);
                elist[row_start[d] + pos] = src[i];
            }
        }
    } else {
        int j = (b - fb) * 256 + threadIdx.x;   // flat slot: v*32 + s
        if (j < n * 32) {
            int v = j >> 5, s = j & 31;
            int p = s >> 4, c = s & 15;
            float d = rsqrtf((float)(cnt[v] + 1));
            float f0, f1;
            if (*flag != 0) {
                uint32 u = ((const uint32*)xv)[j];
                f0 = bf_lo(u) * d; f1 = bf_hi(u) * d;
            } else {
                float2 tt = ((const float2*)xv)[j];
                f0 = tt.x * d; f1 = tt.y * d;
            }
            xs[(size_t)p * n * 16 + (size_t)v * 16 + c] = pack_bf(f0, f1);
            if (s == 0) dinv[v] = d;
        }
    }
}

// ---------------- aggregation: plane-split, one wave per (node,plane) ------
// feat: [2][n][16] uint32 planes. plane = blockIdx&1 (XCD round-robin pins a
// plane per XCD's L2). 16 lanes per half-row -> 4 edges per gather instr;
// one 64-edge elist load covers the neighborhood; shfl_xor(16,32) row fold.
// Output written FLAT ([n,32] uint32 or [n,32] float2 rows).

template <bool BIAS, bool OUT_NATIVE>
__global__ __launch_bounds__(256) void agg_k(
    const uint32* __restrict__ feat, const float* __restrict__ dinv,
    const int* __restrict__ row_start, const int* __restrict__ elist,
    const float* __restrict__ bias, void* __restrict__ outv,
    const int* __restrict__ flag, int n) {
    const int p = blockIdx.x & 1;
    const int v = (blockIdx.x >> 1) * 4 + (threadIdx.x >> 6);
    if (v >= n) return;
    const int L = threadIdx.x & 63;
    const int r = L >> 4;      // row slot 0..3 (edge within 4-group)
    const int j = L & 15;      // uint32 col within half-row
    const uint32* plane = feat + (size_t)p * n * 16;

    const int rs = row_start[v], re = row_start[v + 1];
    const float dv = dinv[v];

    uint32 su = plane[(size_t)v * 16 + j];
    float acc0 = (r == 0) ? bf_lo(su) : 0.f;
    float acc1 = (r == 0) ? bf_hi(su) : 0.f;

    for (int base = rs; base < re; base += 64) {
        int ed = elist[min(base + L, re - 1)];   // 64 edges, one per lane
#pragma unroll
        for (int k = 0; k < 16; ++k) {           // 4 edges per step
            int jb = base + k * 4;
            if (jb >= re) break;                 // wave-uniform
            int s = __shfl(ed, k * 4 + r);
            float wt = (jb + r < re) ? 1.f : 0.f;
            uint32 u = plane[(size_t)s * 16 + j];
            acc0 = fmaf(wt, bf_lo(u), acc0);
            acc1 = fmaf(wt, bf_hi(u), acc1);
        }
    }

    acc0 += __shfl_xor(acc0, 16); acc1 += __shfl_xor(acc1, 16);
    acc0 += __shfl_xor(acc0, 32); acc1 += __shfl_xor(acc1, 32);

    if (L < 16) {
        float bv0 = 0.f, bv1 = 0.f;
        if constexpr (BIAS) { bv0 = bias[p * 32 + 2 * j]; bv1 = bias[p * 32 + 2 * j + 1]; }
        float val0 = fmaf(dv, acc0, bv0);
        float val1 = fmaf(dv, acc1, bv1);
        if constexpr (OUT_NATIVE) {
            if (*flag != 0) ((uint32*)outv)[(size_t)v * 32 + p * 16 + j] = pack_bf(val0, val1);
            else            ((float2*)outv)[(size_t)v * 32 + p * 16 + j] = make_float2(val0, val1);
        } else {
            ((uint32*)outv)[(size_t)v * 32 + p * 16 + j] = pack_bf(val0, val1);
        }
    }
}

// ---------------- BN stats over bf16 flat [n,C] buffer (C2 = C/2) ----------

template <int C2>
__global__ __launch_bounds__(256) void stat_k(const uint32* __restrict__ buf,
                                              float* __restrict__ stats, int n) {
    constexpr int RPB = 256 / C2;
    constexpr int C = 2 * C2;
    const int lp = threadIdx.x % C2;
    const int rg = threadIdx.x / C2;
    float s0 = 0.f, s1 = 0.f, q0 = 0.f, q1 = 0.f;
    for (int r = blockIdx.x * RPB + rg; r < n; r += gridDim.x * RPB) {
        uint32 u = buf[(size_t)r * C2 + lp];
        float f0 = bf_lo(u), f1 = bf_hi(u);
        s0 += f0; q0 = fmaf(f0, f0, q0);
        s1 += f1; q1 = fmaf(f1, f1, q1);
    }
    __shared__ float sd[2 * C];
    for (int i = threadIdx.x; i < 2 * C; i += 256) sd[i] = 0.f;
    __syncthreads();
    atomicAdd(&sd[2 * lp], s0);
    atomicAdd(&sd[2 * lp + 1], s1);
    atomicAdd(&sd[C + 2 * lp], q0);
    atomicAdd(&sd[C + 2 * lp + 1], q1);
    __syncthreads();
    for (int i = threadIdx.x; i < 2 * C; i += 256) atomicAdd(&stats[i], sd[i]);
}

// ---------------- GEMM: out = epilogue( act(A) @ W ) ----------------
// A [n,K] bf16 flat, W [K,N] f32, out bf16 (flat or plane-split).
// AFFS: in-block BN coefs from raw stats+gamma+beta, BN+leaky on load.
// BIAS: add bias[col]. DINV: scale row by dinv[row]. SPLIT: plane-split store.

template <int K, int N, int MR, bool AFFS, bool BIAS, bool DINV, bool SPLIT>
__global__ __launch_bounds__(256) void gemm_k(
    const __hip_bfloat16* __restrict__ A, const float* __restrict__ W,
    const float* __restrict__ stats, const float* __restrict__ g,
    const float* __restrict__ be, float invN,
    const float* __restrict__ bias, const float* __restrict__ dinv,
    __hip_bfloat16* __restrict__ out, int n) {
    constexpr int CG = N / 4;        // threads across columns
    constexpr int RG = 256 / CG;     // row groups
    constexpr int TM = RG * MR;      // rows per block
    constexpr int AP = TM + 4;       // padded row (16B-aligned stride)
    __shared__ __align__(16) float Ws[K * N];
    __shared__ __align__(16) float Ast[K][AP];
    __shared__ float cf[AFFS ? 2 * K : 1];

    const int tid = threadIdx.x;
    if constexpr (AFFS) {
        if (tid < K) {
            float mean = stats[tid] * invN;
            float var  = fmaxf(fmaf(-mean, mean, stats[K + tid] * invN), 0.f);
            float a    = g[tid] * rsqrtf(var + EPS_BN);
            cf[tid]     = a;
            cf[K + tid] = be[tid] - mean * a;
        }
        __syncthreads();
    }

    for (int i = tid; i < K * N / 4; i += 256)
        ((float4*)Ws)[i] = ((const float4*)W)[i];

    const int row0 = blockIdx.x * TM;
    constexpr int KC = K / 4;
    for (int i = tid; i < TM * KC; i += 256) {
        int r  = i / KC;
        int c4 = (i - r * KC) * 4;
        int gr = row0 + r;
        float f0 = 0.f, f1 = 0.f, f2 = 0.f, f3 = 0.f;
        if (gr < n) {
            uint2 u = *(const uint2*)(A + (size_t)gr * K + c4);
            f0 = bf_lo(u.x); f1 = bf_hi(u.x);
            f2 = bf_lo(u.y); f3 = bf_hi(u.y);
            if constexpr (AFFS) {
                f0 = fmaf(cf[c4 + 0], f0, cf[K + c4 + 0]); f0 = f0 > 0.f ? f0 : LEAKY * f0;
                f1 = fmaf(cf[c4 + 1], f1, cf[K + c4 + 1]); f1 = f1 > 0.f ? f1 : LEAKY * f1;
                f2 = fmaf(cf[c4 + 2], f2, cf[K + c4 + 2]); f2 = f2 > 0.f ? f2 : LEAKY * f2;
                f3 = fmaf(cf[c4 + 3], f3, cf[K + c4 + 3]); f3 = f3 > 0.f ? f3 : LEAKY * f3;
            }
        }
        Ast[c4 + 0][r] = f0; Ast[c4 + 1][r] = f1;
        Ast[c4 + 2][r] = f2; Ast[c4 + 3][r] = f3;
    }
    __syncthreads();

    const int tr = tid / CG, tc = tid % CG;
    float acc[MR][4];
#pragma unroll
    for (int m = 0; m < MR; ++m)
#pragma unroll
        for (int j = 0; j < 4; ++j) acc[m][j] = 0.f;

#pragma unroll 4
    for (int k = 0; k < K; ++k) {
        float4 w = *(const float4*)&Ws[k * N + tc * 4];
        float am[MR];
        if constexpr (MR == 4) {
            float4 t = *(const float4*)&Ast[k][tr * 4];
            am[0] = t.x; am[1] = t.y; am[2] = t.z; am[3] = t.w;
        } else {
            float2 t = *(const float2*)&Ast[k][tr * 2];
            am[0] = t.x; am[1] = t.y;
        }
#pragma unroll
        for (int m = 0; m < MR; ++m) {
            acc[m][0] = fmaf(am[m], w.x, acc[m][0]);
            acc[m][1] = fmaf(am[m], w.y, acc[m][1]);
            acc[m][2] = fmaf(am[m], w.z, acc[m][2]);
            acc[m][3] = fmaf(am[m], w.w, acc[m][3]);
        }
    }

    float bv[4] = {0.f, 0.f, 0.f, 0.f};
    if constexpr (BIAS) {
#pragma unroll
        for (int j = 0; j < 4; ++j) bv[j] = bias[tc * 4 + j];
    }

#pragma unroll
    for (int m = 0; m < MR; ++m) {
        int gr = row0 + tr * MR + m;
        if (gr < n) {
            float sc = 1.f;
            if constexpr (DINV) sc = dinv[gr];
            __attribute__((aligned(8))) __hip_bfloat16 pk[4];
#pragma unroll
            for (int j = 0; j < 4; ++j) {
                float v = acc[m][j];
                if constexpr (BIAS) v += bv[j];
                else                v *= sc;
                pk[j] = __float2bfloat16(v);
            }
            if constexpr (SPLIT) {
                int col4  = tc * 4;
                int plane = col4 >> 5;
                uint32* o = (uint32*)out + (size_t)plane * n * 16 +
                            (size_t)gr * 16 + ((col4 & 31) >> 1);
                *(uint2*)o = *(const uint2*)pk;
            } else {
                *(uint2*)(out + (size_t)gr * N + tc * 4) = *(const uint2*)pk;
            }
        }
    }
}

// ---------------- host ----------------

extern "C" void kernel_launch(void* const* d_in, const int* in_sizes, int n_in,
                              void* d_out, int out_size, void* d_ws, size_t ws_size,
                              hipStream_t stream) {
    const int n = in_sizes[0] / 64;   // 50000
    const int E = in_sizes[1] / 2;    // 800000

    const void* x  = d_in[0];
    const int*  ei = (const int*)d_in[1];

    // workspace carve (256B aligned) — total ~23 MB
    char* w = (char*)d_ws;
    auto alloc = [&](size_t bytes) -> void* {
        void* p = (void*)w;
        w += (bytes + 255) & ~(size_t)255;
        return p;
    };
    const int nchunk = (n + 255) / 256;
    int*   flag      = (int*)alloc(256);
    float* Wf        = (float*)alloc(21120 * 4);          // converted params
    int*   cnt       = (int*)alloc((size_t)n * 4);
    int*   cursor    = (int*)alloc((size_t)n * 4);
    int*   row_start = (int*)alloc((size_t)(n + 1) * 4);
    int*   elist     = (int*)alloc((size_t)E * 4);
    float* dinv      = (float*)alloc((size_t)n * 4);
    int*   csum      = (int*)alloc((size_t)nchunk * 4);
    int*   coff      = (int*)alloc((size_t)nchunk * 4);
    float* stats1    = (float*)alloc(256 * 4);
    float* stats2    = (float*)alloc(128 * 4);
    __hip_bfloat16* B1 = (__hip_bfloat16*)alloc((size_t)n * 64 * 2);   // AX(flat) / hd2,hd3(split)
    __hip_bfloat16* B2 = (__hip_bfloat16*)alloc((size_t)n * 128 * 2);  // xs(split) / out1 / out2
    uint32* xs = (uint32*)B2;   // xs aliases B2: consumed by agg1 before gemm1 writes B2

    // param offsets inside Wf
    float* W1f = Wf + 0;     float* b1f = Wf + 8192;
    float* g1f = Wf + 8320;  float* be1f = Wf + 8448;
    float* W2f = Wf + 8576;  float* b2f = Wf + 16768;
    float* g2f = Wf + 16832; float* be2f = Wf + 16896;
    float* W3f = Wf + 16960; float* b3f = Wf + 21056;

    const float invN = 1.0f / (float)n;
    const int zb = (2 * n + 384 + 255) / 256;
    const int fb = 2048;                 // binned-scatter blocks (256 per bin)
    const int xb = (n * 32 + 255) / 256;
    const int ab = 2 * ((n + 3) / 4);    // (node,plane) waves, 4 nodes/block

    // 1: zero + detect + cvt params
    setup_k<<<83 + zb, 256, 0, stream>>>((const uint32*)x, flag,
        d_in[2], d_in[3], d_in[4], d_in[5], d_in[6], d_in[7], d_in[8], d_in[9],
        d_in[10], d_in[11], Wf, cnt, cursor, stats1, stats2, n);
    // 2-5: CSR
    hist_bin_k<<<fb, 256, 0, stream>>>(ei + E, cnt, E, n);
    chunk_sum_k<<<nchunk, 256, 0, stream>>>(cnt, csum, n);
    chunk_scan_k<<<1, 256, 0, stream>>>(csum, coff, nchunk, row_start + n, E);
    local_scan_k<<<nchunk, 256, 0, stream>>>(cnt, coff, row_start, n);
    // 6: binned elist fill + dinv + xs (plane-split)
    build_k<<<fb + xb, 256, 0, stream>>>(ei, ei + E, row_start, cursor, elist,
                                         cnt, x, flag, xs, dinv, E, n, fb);

    // Layer 1 (aggregate-first): B1 = A_hat x (flat) ; out1(B2) = B1@W1 + b1 ; stats1
    agg_k<false, false><<<ab, 256, 0, stream>>>(xs, dinv, row_start, elist,
                                                nullptr, B1, flag, n);
    gemm_k<64, 128, 4, false, true, false, false><<<(n + 31) / 32, 256, 0, stream>>>(
        B1, W1f, nullptr, nullptr, nullptr, 0.f, b1f, nullptr, B2, n);
    stat_k<64><<<256, 256, 0, stream>>>((const uint32*)B2, stats1, n);

    // Layer 2: hd2(B1,split) = (BN+leaky(out1)@W2)*dinv ; out2(B2,flat) = gather+b2 ; stats2
    gemm_k<128, 64, 2, true, false, true, true><<<(n + 31) / 32, 256, 0, stream>>>(
        B2, W2f, stats1, g1f, be1f, invN, nullptr, dinv, B1, n);
    agg_k<true, false><<<ab, 256, 0, stream>>>((const uint32*)B1, dinv, row_start,
                                               elist, b2f, B2, flag, n);
    stat_k<32><<<256, 256, 0, stream>>>((const uint32*)B2, stats2, n);

    // Layer 3: hd3(B1,split) = (BN+leaky(out2)@W3)*dinv ; out = gather + b3 (native)
    gemm_k<64, 64, 4, true, false, true, true><<<(n + 63) / 64, 256, 0, stream>>>(
        B2, W3f, stats2, g2f, be2f, invN, nullptr, dinv, B1, n);
    agg_k<true, true><<<ab, 256, 0, stream>>>((const uint32*)B1, dinv, row_start,
                                              elist, b3f, d_out, flag, n);
}

// Round 9
// 297.401 us; speedup vs baseline: 1.3254x; 1.3254x over previous
//
#include <hip/hip_runtime.h>
#include <hip/hip_bf16.h>

// ---------------------------------------------------------------------------
// GCNEncoder: 3x (GCNConv -> [BN -> LeakyReLU]), N=50000 nodes, E=800000 edges.
//   Layer1 aggregate-first:  out1 = (A_hat X) W1 + b1
//   Layers2/3 transform-first: hd = (act(prev) @ W) * dinv; out = gather + bias
// R9: revert R8 plane-split (regressed 331->394: XCD mapping undefined).
//     Atomic-free radix CSR build replaces hist+scans+fill (R6 evidence:
//     build_k 47-50us from 800k random global atomics + scattered stores):
//       cnt1_k: per-(block,bin) LDS histogram        (no global atomics)
//       scan2_k: exact offsets via one-block scan    (no atomics)
//       scat_k: bucket-partition edges, LDS cursors  (no global atomics)
//       fill2_k: per-bin CSR + elist (L2-local window) + fused xs/dinv
// ---------------------------------------------------------------------------

#define LEAKY 0.01f
#define EPS_BN 1e-5f
#define NBIN 256
#define CB   128

typedef unsigned int uint32;

static __device__ __forceinline__ float bf_lo(uint32 u) { return __uint_as_float(u << 16); }
static __device__ __forceinline__ float bf_hi(uint32 u) { return __uint_as_float(u & 0xFFFF0000u); }

static __device__ __forceinline__ uint32 pack_bf(float x, float y) {
    __hip_bfloat16 bx = __float2bfloat16(x), by = __float2bfloat16(y);
    return (uint32)(*(unsigned short*)&bx) | ((uint32)(*(unsigned short*)&by) << 16);
}

// ---------------- setup: detect dtype + convert params + zero stats ---------
// blocks [0,83): detect flag (redundant per block) + convert param slice
// block 83: zero stats1/stats2
// param dst layout: W1@0(8192) b1@8192(128) g1@8320(128) be1@8448(128)
//   W2@8576(8192) b2@16768(64) g2@16832(64) be2@16896(64) W3@16960(4096) b3@21056(64)

__global__ void setup_k(const uint32* __restrict__ x, int* __restrict__ flag,
                        const void* p0, const void* p1, const void* p2,
                        const void* p3, const void* p4, const void* p5,
                        const void* p6, const void* p7, const void* p8,
                        const void* p9, float* __restrict__ dst,
                        float* __restrict__ stats1, float* __restrict__ stats2) {
    const int b = blockIdx.x, t = threadIdx.x;
    if (b < 83) {
        __shared__ int sd[256];
        int c = 0;
        for (int j = 0; j < 16; ++j) {
            uint32 w = x[t * 16 + j];
            uint32 m = w & 0x7FFFu;
            uint32 e = (w >> 7) & 0xFFu;
            if (m == 0u || (e >= 100u && e <= 150u)) ++c;
        }
        sd[t] = c;
        __syncthreads();
        for (int off = 128; off > 0; off >>= 1) {
            if (t < off) sd[t] += sd[t + off];
            __syncthreads();
        }
        bool bf = (sd[0] >= 3072);
        if (b == 0 && t == 0) *flag = bf ? 1 : 0;
        int i = b * 256 + t;
        if (i < 21120) {
            const void* p;
            int j;
            if      (i <  8192) { p = p0; j = i;         }
            else if (i <  8320) { p = p1; j = i - 8192;  }
            else if (i <  8448) { p = p2; j = i - 8320;  }
            else if (i <  8576) { p = p3; j = i - 8448;  }
            else if (i < 16768) { p = p4; j = i - 8576;  }
            else if (i < 16832) { p = p5; j = i - 16768; }
            else if (i < 16896) { p = p6; j = i - 16832; }
            else if (i < 16960) { p = p7; j = i - 16896; }
            else if (i < 21056) { p = p8; j = i - 16960; }
            else                { p = p9; j = i - 21056; }
            dst[i] = bf ? __bfloat162float(((const __hip_bfloat16*)p)[j])
                        : ((const float*)p)[j];
        }
    } else {
        stats1[t] = 0.f;
        if (t < 128) stats2[t] = 0.f;
    }
}

// ---------------- radix CSR build, atomic-free (global) ----------------
// bins = node ranges of npb nodes; pbc[b][j] = count of block b's edges in bin j.

__global__ __launch_bounds__(256) void cnt1_k(const int* __restrict__ dst,
                                              int* __restrict__ pbc, int E, int npb) {
    __shared__ int c[NBIN];
    c[threadIdx.x] = 0;
    __syncthreads();
    const int chunk = (E + CB - 1) / CB;
    const int lo = blockIdx.x * chunk, hi = min(E, lo + chunk);
    for (int i = lo + threadIdx.x; i < hi; i += 256)
        atomicAdd(&c[dst[i] / npb], 1);
    __syncthreads();
    pbc[blockIdx.x * NBIN + threadIdx.x] = c[threadIdx.x];
}

// one block, 256 threads (thread j owns bin j)
__global__ __launch_bounds__(256) void scan2_k(int* __restrict__ pbc,
                                               int* __restrict__ bb,
                                               int* __restrict__ row_end, int E) {
    const int j = threadIdx.x;
    int tot = 0;
    for (int b = 0; b < CB; ++b) tot += pbc[b * NBIN + j];
    __shared__ int sd[NBIN];
    sd[j] = tot;
    __syncthreads();
    for (int off = 1; off < NBIN; off <<= 1) {
        int x = (j >= off) ? sd[j - off] : 0;
        __syncthreads();
        sd[j] += x;
        __syncthreads();
    }
    int base = sd[j] - tot;   // exclusive bucket base
    bb[j] = base;
    if (j == 0) { bb[NBIN] = E; *row_end = E; }
    int run = base;
    for (int b = 0; b < CB; ++b) {
        int v = pbc[b * NBIN + j];
        pbc[b * NBIN + j] = run;
        run += v;
    }
}

__global__ __launch_bounds__(256) void scat_k(const int* __restrict__ src,
                                              const int* __restrict__ dst,
                                              const int* __restrict__ pbc,
                                              int2* __restrict__ ebuf, int E, int npb) {
    __shared__ int cur[NBIN];
    cur[threadIdx.x] = pbc[blockIdx.x * NBIN + threadIdx.x];
    __syncthreads();
    const int chunk = (E + CB - 1) / CB;
    const int lo = blockIdx.x * chunk, hi = min(E, lo + chunk);
    for (int i = lo + threadIdx.x; i < hi; i += 256) {
        int d = dst[i];
        int p = atomicAdd(&cur[d / npb], 1);     // LDS atomic
        ebuf[p] = make_int2(src[i], d);
    }
}

// one block per bin: CSR rows + elist for its node range + fused xs/dinv.
__global__ __launch_bounds__(256) void fill2_k(
    const int2* __restrict__ ebuf, const int* __restrict__ bb,
    int* __restrict__ row_start, int* __restrict__ elist,
    const void* __restrict__ xv, const int* __restrict__ flag,
    uint32* __restrict__ xs, float* __restrict__ dinv, int n, int npb) {
    __shared__ int cntl[NBIN], curl[NBIN], sd[NBIN];
    const int j = blockIdx.x, t = threadIdx.x;
    const int lo = j * npb;
    const int hi = min(n, lo + npb);
    const int nn = hi - lo;
    if (nn <= 0) return;
    const int eb = bb[j], ee = bb[j + 1];

    cntl[t] = 0;
    __syncthreads();
    for (int i = eb + t; i < ee; i += 256)
        atomicAdd(&cntl[ebuf[i].y - lo], 1);     // LDS atomic
    __syncthreads();
    int cv = cntl[t];
    sd[t] = cv;
    __syncthreads();
    for (int off = 1; off < NBIN; off <<= 1) {
        int x = (t >= off) ? sd[t - off] : 0;
        __syncthreads();
        sd[t] += x;
        __syncthreads();
    }
    int pref = sd[t] - cv;                        // exclusive
    if (t < nn) row_start[lo + t] = eb + pref;
    curl[t] = pref;
    __syncthreads();
    for (int i = eb + t; i < ee; i += 256) {
        int2 e = ebuf[i];
        int p = atomicAdd(&curl[e.y - lo], 1);    // LDS atomic
        elist[eb + p] = e.x;                      // L2-local window (~100KB)
    }
    // xs = x * dinv (bf16 packed, flat [n][32] uint32) + dinv, for this range
    const bool bf = (*flag != 0);
    for (int idx = t; idx < nn * 32; idx += 256) {
        int v = lo + (idx >> 5), s = idx & 31;
        float d = rsqrtf((float)(cntl[v - lo] + 1));
        float f0, f1;
        if (bf) {
            uint32 u = ((const uint32*)xv)[(size_t)v * 32 + s];
            f0 = bf_lo(u) * d; f1 = bf_hi(u) * d;
        } else {
            float2 tt = ((const float2*)xv)[(size_t)v * 32 + s];
            f0 = tt.x * d; f1 = tt.y * d;
        }
        xs[(size_t)v * 32 + s] = pack_bf(f0, f1);
        if (s == 0) dinv[v] = d;
    }
}

// ---------------- aggregation: one wave per node (R7 version) ----------------
// feat: [n,64] bf16 packed as [n,32] uint32. out[v] = dinv[v]*gather + bias.
// ONE coalesced 64-edge elist load covers the neighborhood (P(deg>64)~0);
// gather sub-batches depend only on it. Lanes 0-31 even / 32-63 odd edges,
// 2 channels per lane, shfl_xor(32) fold.

template <bool BIAS, bool OUT_NATIVE>
__global__ __launch_bounds__(256) void agg_k(
    const uint32* __restrict__ feat, const float* __restrict__ dinv,
    const int* __restrict__ row_start, const int* __restrict__ elist,
    const float* __restrict__ bias, void* __restrict__ outv,
    const int* __restrict__ flag, int n) {
    const int v = blockIdx.x * 4 + (threadIdx.x >> 6);
    if (v >= n) return;
    const int L   = threadIdx.x & 63;
    const int l32 = L & 31;
    const int h   = L >> 5;

    const int rs = row_start[v], re = row_start[v + 1];
    const float dv = dinv[v];

    uint32 su = feat[(size_t)v * 32 + l32];
    float acc0 = (h == 0) ? bf_lo(su) : 0.f;
    float acc1 = (h == 0) ? bf_hi(su) : 0.f;

    for (int base = rs; base < re; base += 64) {
        int ed = elist[min(base + L, re - 1)];   // 64 edges, one per lane
#pragma unroll 1
        for (int k = 0; k < 4; ++k) {            // wave-uniform sub-batches
            int b16 = base + k * 16;
            if (b16 >= re) break;
#pragma unroll
            for (int t = 0; t < 8; ++t) {
                int j = k * 16 + 2 * t + h;
                int s = __shfl(ed, j);
                float wt = (base + j < re) ? 1.f : 0.f;
                uint32 u = feat[(size_t)s * 32 + l32];
                acc0 = fmaf(wt, bf_lo(u), acc0);
                acc1 = fmaf(wt, bf_hi(u), acc1);
            }
        }
    }

    acc0 += __shfl_xor(acc0, 32);
    acc1 += __shfl_xor(acc1, 32);

    float bv0 = 0.f, bv1 = 0.f;
    if constexpr (BIAS) { bv0 = bias[l32 * 2]; bv1 = bias[l32 * 2 + 1]; }
    float val0 = fmaf(dv, acc0, bv0);
    float val1 = fmaf(dv, acc1, bv1);

    if (h == 0) {
        if constexpr (OUT_NATIVE) {
            if (*flag != 0) ((uint32*)outv)[(size_t)v * 32 + l32] = pack_bf(val0, val1);
            else            ((float2*)outv)[(size_t)v * 32 + l32] = make_float2(val0, val1);
        } else {
            ((uint32*)outv)[(size_t)v * 32 + l32] = pack_bf(val0, val1);
        }
    }
}

// ---------------- BN stats over bf16 [n,C] buffer (C2 = C/2 uint32/row) ----

template <int C2>
__global__ __launch_bounds__(256) void stat_k(const uint32* __restrict__ buf,
                                              float* __restrict__ stats, int n) {
    constexpr int RPB = 256 / C2;
    constexpr int C = 2 * C2;
    const int lp = threadIdx.x % C2;
    const int rg = threadIdx.x / C2;
    float s0 = 0.f, s1 = 0.f, q0 = 0.f, q1 = 0.f;
    for (int r = blockIdx.x * RPB + rg; r < n; r += gridDim.x * RPB) {
        uint32 u = buf[(size_t)r * C2 + lp];
        float f0 = bf_lo(u), f1 = bf_hi(u);
        s0 += f0; q0 = fmaf(f0, f0, q0);
        s1 += f1; q1 = fmaf(f1, f1, q1);
    }
    __shared__ float sd[2 * C];
    for (int i = threadIdx.x; i < 2 * C; i += 256) sd[i] = 0.f;
    __syncthreads();
    atomicAdd(&sd[2 * lp], s0);
    atomicAdd(&sd[2 * lp + 1], s1);
    atomicAdd(&sd[C + 2 * lp], q0);
    atomicAdd(&sd[C + 2 * lp + 1], q1);
    __syncthreads();
    for (int i = threadIdx.x; i < 2 * C; i += 256) atomicAdd(&stats[i], sd[i]);
}

// ---------------- GEMM: out = epilogue( act(A) @ W ) ----------------
// A [n,K] bf16 flat, W [K,N] f32, out [n,N] bf16 flat. A-tile transposed in LDS.
// AFFS: in-block BN coefs from raw stats+gamma+beta, BN+leaky on load.
// BIAS: add bias[col]. DINV: scale row by dinv[row].

template <int K, int N, int MR, bool AFFS, bool BIAS, bool DINV>
__global__ __launch_bounds__(256) void gemm_k(
    const __hip_bfloat16* __restrict__ A, const float* __restrict__ W,
    const float* __restrict__ stats, const float* __restrict__ g,
    const float* __restrict__ be, float invN,
    const float* __restrict__ bias, const float* __restrict__ dinv,
    __hip_bfloat16* __restrict__ out, int n) {
    constexpr int CG = N / 4;        // threads across columns
    constexpr int RG = 256 / CG;     // row groups
    constexpr int TM = RG * MR;      // rows per block
    constexpr int AP = TM + 4;       // padded row (16B-aligned stride)
    __shared__ __align__(16) float Ws[K * N];
    __shared__ __align__(16) float Ast[K][AP];
    __shared__ float cf[AFFS ? 2 * K : 1];

    const int tid = threadIdx.x;
    if constexpr (AFFS) {
        if (tid < K) {
            float mean = stats[tid] * invN;
            float var  = fmaxf(fmaf(-mean, mean, stats[K + tid] * invN), 0.f);
            float a    = g[tid] * rsqrtf(var + EPS_BN);
            cf[tid]     = a;
            cf[K + tid] = be[tid] - mean * a;
        }
        __syncthreads();
    }

    for (int i = tid; i < K * N / 4; i += 256)
        ((float4*)Ws)[i] = ((const float4*)W)[i];

    const int row0 = blockIdx.x * TM;
    constexpr int KC = K / 4;
    for (int i = tid; i < TM * KC; i += 256) {
        int r  = i / KC;
        int c4 = (i - r * KC) * 4;
        int gr = row0 + r;
        float f0 = 0.f, f1 = 0.f, f2 = 0.f, f3 = 0.f;
        if (gr < n) {
            uint2 u = *(const uint2*)(A + (size_t)gr * K + c4);
            f0 = bf_lo(u.x); f1 = bf_hi(u.x);
            f2 = bf_lo(u.y); f3 = bf_hi(u.y);
            if constexpr (AFFS) {
                f0 = fmaf(cf[c4 + 0], f0, cf[K + c4 + 0]); f0 = f0 > 0.f ? f0 : LEAKY * f0;
                f1 = fmaf(cf[c4 + 1], f1, cf[K + c4 + 1]); f1 = f1 > 0.f ? f1 : LEAKY * f1;
                f2 = fmaf(cf[c4 + 2], f2, cf[K + c4 + 2]); f2 = f2 > 0.f ? f2 : LEAKY * f2;
                f3 = fmaf(cf[c4 + 3], f3, cf[K + c4 + 3]); f3 = f3 > 0.f ? f3 : LEAKY * f3;
            }
        }
        Ast[c4 + 0][r] = f0; Ast[c4 + 1][r] = f1;
        Ast[c4 + 2][r] = f2; Ast[c4 + 3][r] = f3;
    }
    __syncthreads();

    const int tr = tid / CG, tc = tid % CG;
    float acc[MR][4];
#pragma unroll
    for (int m = 0; m < MR; ++m)
#pragma unroll
        for (int j = 0; j < 4; ++j) acc[m][j] = 0.f;

#pragma unroll 4
    for (int k = 0; k < K; ++k) {
        float4 w = *(const float4*)&Ws[k * N + tc * 4];
        float am[MR];
        if constexpr (MR == 4) {
            float4 t = *(const float4*)&Ast[k][tr * 4];
            am[0] = t.x; am[1] = t.y; am[2] = t.z; am[3] = t.w;
        } else {
            float2 t = *(const float2*)&Ast[k][tr * 2];
            am[0] = t.x; am[1] = t.y;
        }
#pragma unroll
        for (int m = 0; m < MR; ++m) {
            acc[m][0] = fmaf(am[m], w.x, acc[m][0]);
            acc[m][1] = fmaf(am[m], w.y, acc[m][1]);
            acc[m][2] = fmaf(am[m], w.z, acc[m][2]);
            acc[m][3] = fmaf(am[m], w.w, acc[m][3]);
        }
    }

    float bv[4] = {0.f, 0.f, 0.f, 0.f};
    if constexpr (BIAS) {
#pragma unroll
        for (int j = 0; j < 4; ++j) bv[j] = bias[tc * 4 + j];
    }

#pragma unroll
    for (int m = 0; m < MR; ++m) {
        int gr = row0 + tr * MR + m;
        if (gr < n) {
            float sc = 1.f;
            if constexpr (DINV) sc = dinv[gr];
            __attribute__((aligned(8))) __hip_bfloat16 pk[4];
#pragma unroll
            for (int j = 0; j < 4; ++j) {
                float v = acc[m][j];
                if constexpr (BIAS) v += bv[j];
                else                v *= sc;
                pk[j] = __float2bfloat16(v);
            }
            *(uint2*)(out + (size_t)gr * N + tc * 4) = *(const uint2*)pk;
        }
    }
}

// ---------------- host ----------------

extern "C" void kernel_launch(void* const* d_in, const int* in_sizes, int n_in,
                              void* d_out, int out_size, void* d_ws, size_t ws_size,
                              hipStream_t stream) {
    const int n = in_sizes[0] / 64;   // 50000
    const int E = in_sizes[1] / 2;    // 800000

    const void* x  = d_in[0];
    const int*  ei = (const int*)d_in[1];

    // workspace carve (256B aligned) — total ~30 MB
    char* w = (char*)d_ws;
    auto alloc = [&](size_t bytes) -> void* {
        void* p = (void*)w;
        w += (bytes + 255) & ~(size_t)255;
        return p;
    };
    int*   flag      = (int*)alloc(256);
    float* Wf        = (float*)alloc(21120 * 4);            // converted params
    int*   pbc       = (int*)alloc((size_t)CB * NBIN * 4);  // per-(block,bin) counts
    int*   bb        = (int*)alloc((NBIN + 1) * 4);         // bucket bases
    int*   row_start = (int*)alloc((size_t)(n + 1) * 4);
    int*   elist     = (int*)alloc((size_t)E * 4);
    int2*  ebuf      = (int2*)alloc((size_t)E * 8);         // partitioned (src,dst)
    float* dinv      = (float*)alloc((size_t)n * 4);
    float* stats1    = (float*)alloc(256 * 4);
    float* stats2    = (float*)alloc(128 * 4);
    __hip_bfloat16* B1 = (__hip_bfloat16*)alloc((size_t)n * 64 * 2);   // AX / hd2 / hd3
    __hip_bfloat16* B2 = (__hip_bfloat16*)alloc((size_t)n * 128 * 2);  // xs / out1 / out2
    uint32* xs = (uint32*)B2;   // xs aliases B2: consumed by agg1 before gemm1 writes B2

    // param offsets inside Wf
    float* W1f = Wf + 0;     float* b1f = Wf + 8192;
    float* g1f = Wf + 8320;  float* be1f = Wf + 8448;
    float* W2f = Wf + 8576;  float* b2f = Wf + 16768;
    float* g2f = Wf + 16832; float* be2f = Wf + 16896;
    float* W3f = Wf + 16960; float* b3f = Wf + 21056;

    const float invN = 1.0f / (float)n;
    const int npb = (n + NBIN - 1) / NBIN;   // nodes per bin (196)
    const int ab  = (n + 3) / 4;             // one wave per node, 4 waves/block

    // 1: detect + cvt params + zero stats
    setup_k<<<84, 256, 0, stream>>>((const uint32*)x, flag,
        d_in[2], d_in[3], d_in[4], d_in[5], d_in[6], d_in[7], d_in[8], d_in[9],
        d_in[10], d_in[11], Wf, stats1, stats2);
    // 2-5: atomic-free radix CSR build (+ fused xs/dinv)
    cnt1_k<<<CB, 256, 0, stream>>>(ei + E, pbc, E, npb);
    scan2_k<<<1, 256, 0, stream>>>(pbc, bb, row_start + n, E);
    scat_k<<<CB, 256, 0, stream>>>(ei, ei + E, pbc, ebuf, E, npb);
    fill2_k<<<NBIN, 256, 0, stream>>>(ebuf, bb, row_start, elist, x, flag,
                                      xs, dinv, n, npb);

    // Layer 1 (aggregate-first): B1 = A_hat x ; out1(B2) = B1@W1 + b1 ; stats1
    agg_k<false, false><<<ab, 256, 0, stream>>>(xs, dinv, row_start, elist,
                                                nullptr, B1, flag, n);
    gemm_k<64, 128, 4, false, true, false><<<(n + 31) / 32, 256, 0, stream>>>(
        B1, W1f, nullptr, nullptr, nullptr, 0.f, b1f, nullptr, B2, n);
    stat_k<64><<<256, 256, 0, stream>>>((const uint32*)B2, stats1, n);

    // Layer 2: hd2(B1) = (BN+leaky(out1)@W2)*dinv ; out2(B2) = gather + b2 ; stats2
    gemm_k<128, 64, 2, true, false, true><<<(n + 31) / 32, 256, 0, stream>>>(
        B2, W2f, stats1, g1f, be1f, invN, nullptr, dinv, B1, n);
    agg_k<true, false><<<ab, 256, 0, stream>>>((const uint32*)B1, dinv, row_start,
                                               elist, b2f, B2, flag, n);
    stat_k<32><<<256, 256, 0, stream>>>((const uint32*)B2, stats2, n);

    // Layer 3: hd3(B1) = (BN+leaky(out2)@W3)*dinv ; out = gather + b3 (native)
    gemm_k<64, 64, 4, true, false, true><<<(n + 63) / 64, 256, 0, stream>>>(
        B2, W3f, stats2, g2f, be2f, invN, nullptr, dinv, B1, n);
    agg_k<true, true><<<ab, 256, 0, stream>>>((const uint32*)B1, dinv, row_start,
                                              elist, b3f, d_out, flag, n);
}